// Round 5
// baseline (547.101 us; speedup 1.0000x reference)
//
#include <hip/hip_runtime.h>
#include <stdint.h>

// ---------------------------------------------------------------------------
// Dual attention (DANet): pos attention + channel attention, fused pipeline.
// B=8, C=512, CQ=64, H=W=64, HW=4096.  All GEMMs bf16 MFMA 16x16x32, fp32 acc.
//
// pos_out[c,j] = sum_i v'[c,i] * exp(e[i,j]),  v' = (Wv x + b) * rcp_l[i],
//   rcp_l[i] = 1 / sum_j exp(e[i,j])   (no max subtraction: |e| <~ 13)
// LOG2E folded into wq/pq_b at convert time -> exp2 direct.
//
// v6: v5 layouts (all VMEM loads dense bursts) +
//   rowsum regridded for occupancy (256-thr blocks, i-tile 64, 4 blocks/CU),
//   ce split-K x32 (full CU coverage), setprio(1) around PV MFMA cluster.
// pos_attn: 8-wave blocks, j-tile 64, c-tile 512, double-buffered P^T in LDS,
// ONE barrier per i-iter; chan_out GEMM fused into epilogue (out written once).
// NOTE: pos_attn register budget is EXACTLY 64 arch + 64 acc = 128 = the
// 4-wave/SIMD boundary.  Do not add live state to pos_attn.
// ---------------------------------------------------------------------------

#define LOG2E 1.44269504088896340736f

typedef __attribute__((ext_vector_type(8))) __bf16 bf16x8;
typedef __attribute__((ext_vector_type(4))) float floatx4;
typedef __attribute__((ext_vector_type(2))) float floatx2;
typedef __attribute__((ext_vector_type(2))) unsigned int uint2v;

static __device__ __forceinline__ unsigned short f2bf(float f) {
    union { float f; uint32_t u; } v; v.f = f;
    uint32_t r = v.u + 0x7fffu + ((v.u >> 16) & 1u);   // RNE
    return (unsigned short)(r >> 16);
}

// pack two fp32 -> bf16x2 (round-half-up: +0x8000, take high16 via v_perm)
static __device__ __forceinline__ unsigned int pack_bf16(float a, float b) {
    union { float f; uint32_t u; } x, y; x.f = a; y.f = b;
    return __builtin_amdgcn_perm(y.u + 0x8000u, x.u + 0x8000u, 0x07060302u);
}

// ---------------------------------------------------------------------------
// Generic TN GEMM: C[m,n] = (sum_k A[m,k]*B[n,k] + bias_m[m] + bias_n[n])
//                  * scale_n[n].   A,B bf16 K-contiguous. BK=64.
// SPECIAL=1 (VTILE): write C in pos_attn's V-fragment-linear layout
//   idx = (n>>7)*65536 + (m>>4)*2048 + ((n>>5)&3)*512 + (m&15)*32
//       + ((n>>3)&3)*8 + (n&7)     (m = c, n = i)
// SPECIAL=2 (QKV split): n<64 -> q_lin frag-linear; n in [64,192) ->
//   kT/cvT row-major lda 64 at base (n>>6)*262144.
// ---------------------------------------------------------------------------
template<int BM, int BN, bool OUT_BF16, bool ATOMIC, int SPECIAL = 0>
__global__ __launch_bounds__(256) void tn_gemm(
    const unsigned short* __restrict__ A, int lda, long sA,
    const unsigned short* __restrict__ B, int ldb, long sB,
    void* __restrict__ C, int ldc, long sC,
    const float* __restrict__ bias_m, const float* __restrict__ bias_n,
    const float* __restrict__ scale_n, long sScale,
    int K, int kchunks)
{
    constexpr int PK = 72;                 // 64 + 8 pad
    __shared__ unsigned short As[BM * PK];
    __shared__ unsigned short Bs[BN * PK];
    const int bz = blockIdx.z;
    const int b  = bz / kchunks;
    const int kc = bz % kchunks;
    const int m0 = blockIdx.y * BM;
    const int n0 = blockIdx.x * BN;
    const unsigned short* Ab = A + (long)b * sA + (long)m0 * lda + (long)kc * K;
    const unsigned short* Bb = B + (long)b * sB + (long)n0 * ldb + (long)kc * K;
    const int tid = threadIdx.x;
    const int lane = tid & 63, wave = tid >> 6;
    const int l15 = lane & 15, quad = lane >> 4;
    constexpr int NT  = BN / 16;
    constexpr int MPW = BM / 64;
    constexpr int AL  = BM / 32;
    constexpr int BL  = BN / 32;

    const floatx4 vz = {0.f, 0.f, 0.f, 0.f};
    floatx4 acc[MPW][NT];
    for (int i = 0; i < MPW; ++i) for (int j = 0; j < NT; ++j) acc[i][j] = vz;

    const int nK = K >> 6;
    for (int k0 = 0; k0 < nK; ++k0) {
        floatx4 ar[AL], br[BL];
#pragma unroll
        for (int L = 0; L < AL; ++L) {
            int flat = L * 2048 + tid * 8;
            ar[L] = *(const floatx4*)(Ab + (long)(flat >> 6) * lda + (k0 << 6) + (flat & 63));
        }
#pragma unroll
        for (int L = 0; L < BL; ++L) {
            int flat = L * 2048 + tid * 8;
            br[L] = *(const floatx4*)(Bb + (long)(flat >> 6) * ldb + (k0 << 6) + (flat & 63));
        }
        __syncthreads();
#pragma unroll
        for (int L = 0; L < AL; ++L) {
            int flat = L * 2048 + tid * 8;
            *(floatx4*)&As[(flat >> 6) * PK + (flat & 63)] = ar[L];
        }
#pragma unroll
        for (int L = 0; L < BL; ++L) {
            int flat = L * 2048 + tid * 8;
            *(floatx4*)&Bs[(flat >> 6) * PK + (flat & 63)] = br[L];
        }
        __syncthreads();
#pragma unroll
        for (int ks = 0; ks < 2; ++ks) {
            bf16x8 af[MPW];
#pragma unroll
            for (int mi = 0; mi < MPW; ++mi)
                af[mi] = *(const bf16x8*)&As[((wave * MPW + mi) * 16 + l15) * PK + ks * 32 + quad * 8];
#pragma unroll
            for (int nt = 0; nt < NT; ++nt) {
                bf16x8 bf = *(const bf16x8*)&Bs[(nt * 16 + l15) * PK + ks * 32 + quad * 8];
#pragma unroll
                for (int mi = 0; mi < MPW; ++mi)
                    acc[mi][nt] = __builtin_amdgcn_mfma_f32_16x16x32_bf16(af[mi], bf, acc[mi][nt], 0, 0, 0);
            }
        }
    }
    // epilogue (C/D layout: col = lane&15, row = quad*4 + r)
#pragma unroll
    for (int mi = 0; mi < MPW; ++mi) {
        const int mb = m0 + (wave * MPW + mi) * 16 + quad * 4;
#pragma unroll
        for (int nt = 0; nt < NT; ++nt) {
            const int n = n0 + nt * 16 + l15;
            const float bn = bias_n ? bias_n[n] : 0.f;
            const float cs = scale_n ? scale_n[(long)b * sScale + n] : 1.f;
            floatx4 a = acc[mi][nt];
#pragma unroll
            for (int r = 0; r < 4; ++r) {
                const int m = mb + r;
                float v = (a[r] + (bias_m ? bias_m[m] : 0.f) + bn) * cs;
                long idx;
                if (SPECIAL == 1)
                    idx = (long)b * sC + ((long)(n >> 7) * 65536 + (m >> 4) * 2048
                        + ((n >> 5) & 3) * 512 + (m & 15) * 32 + ((n >> 3) & 3) * 8 + (n & 7));
                else if (SPECIAL == 2) {
                    if (n < 64)   // q_lin fragment-linear
                        idx = (long)b * sC + ((long)(m >> 4) * 1024 + (n >> 5) * 512
                            + (m & 15) * 32 + ((n >> 3) & 3) * 8 + (n & 7));
                    else          // kT / cvT row-major lda 64
                        idx = (long)b * sC + (long)(n >> 6) * 262144 + (long)m * 64 + (n & 63);
                } else
                    idx = (long)b * sC + (long)m * ldc + n;
                if (ATOMIC)         atomicAdd((float*)C + idx, v);
                else if (OUT_BF16)  ((unsigned short*)C)[idx] = f2bf(v);
                else                ((float*)C)[idx] = v;
            }
        }
    }
}

// ---------------------------------------------------------------------------
// rcp_l[b,i] = 1 / sum_j exp2(E'[i,j]).  q from q_lin (1KB frag bursts),
// K from kT [4096][64] (linear staging).
// v6: 4-wave blocks, i-tile 64 (16 rows/wave), grid (8,64) = 512 blocks ->
// 4 blocks/CU (LDS 36KB), 4 waves/SIMD (was 1 block/CU = 2 waves/SIMD).
// K-tile 128 double-buffered in LDS, one barrier per tile.
// ---------------------------------------------------------------------------
__global__ __launch_bounds__(256, 4) void rowsum_kernel(
    const unsigned short* __restrict__ qkvT, float* __restrict__ rcl)
{
    __shared__ unsigned short Ks[2][128 * 72];
    const int b  = blockIdx.x;
    const int i0 = blockIdx.y * 64;
    const unsigned short* qv = qkvT + (long)b * 786432;            // q_lin
    const unsigned short* kb = qkvT + (long)b * 786432 + 262144;   // kT
    const int tid = threadIdx.x, lane = tid & 63, wave = tid >> 6;
    const int l15 = lane & 15, quad = lane >> 4;

    bf16x8 af[2];
#pragma unroll
    for (int ks = 0; ks < 2; ++ks)
        af[ks] = *(const bf16x8*)(qv + (long)((i0 >> 4) + wave) * 1024 + ks * 512 + (l15 * 4 + quad) * 8);

    // stage jb=0 tile (128 rows x 64 = 8192 shorts, linear): 4 passes of 256x8
#pragma unroll
    for (int p = 0; p < 4; ++p) {
        int flat = p * 2048 + tid * 8;
        *(floatx4*)&Ks[0][(flat >> 6) * 72 + (flat & 63)] = *(const floatx4*)(kb + flat);
    }
    float rs[4] = {0.f, 0.f, 0.f, 0.f};
    const floatx4 vz = {0.f, 0.f, 0.f, 0.f};
    __syncthreads();

    for (int jb = 0; jb < 32; ++jb) {
        const int cur = jb & 1;
        floatx4 stage[4];
        if (jb < 31) {
#pragma unroll
            for (int p = 0; p < 4; ++p) {
                int flat = p * 2048 + tid * 8;
                stage[p] = *(const floatx4*)(kb + (jb + 1) * 8192 + flat);
            }
        }
        floatx4 e[8];
#pragma unroll
        for (int nt = 0; nt < 8; ++nt) e[nt] = vz;
#pragma unroll
        for (int ks = 0; ks < 2; ++ks)
#pragma unroll
            for (int nt = 0; nt < 8; ++nt) {
                bf16x8 bf = *(const bf16x8*)&Ks[cur][(nt * 16 + l15) * 72 + ks * 32 + quad * 8];
                e[nt] = __builtin_amdgcn_mfma_f32_16x16x32_bf16(af[ks], bf, e[nt], 0, 0, 0);
            }
#pragma unroll
        for (int nt = 0; nt < 8; ++nt)
#pragma unroll
            for (int r = 0; r < 4; ++r)
                rs[r] += exp2f(e[nt][r]);
        if (jb < 31) {
#pragma unroll
            for (int p = 0; p < 4; ++p) {
                int flat = p * 2048 + tid * 8;
                *(floatx4*)&Ks[1 - cur][(flat >> 6) * 72 + (flat & 63)] = stage[p];
            }
        }
        __syncthreads();
    }
#pragma unroll
    for (int r = 0; r < 4; ++r) {
        float v = rs[r];
        v += __shfl_xor(v, 1); v += __shfl_xor(v, 2);
        v += __shfl_xor(v, 4); v += __shfl_xor(v, 8);
        if (l15 == 0)
            rcl[(long)b * 4096 + i0 + wave * 16 + quad * 4 + r] = 1.0f / v;
    }
}

// ---------------------------------------------------------------------------
// Fused position attention + channel-output epilogue (v6: +setprio on PV).
// Block = (batch, j-tile 64), 512 threads (8 waves); c-tile = 512 (full).
// Per i-iter (128): ONE barrier. Region: PV(ib) reads Ps[cur] || E(ib+1)
// writes Ps[1-cur].  E: q frags = 1KB bursts from q_lin;
// PV: V frags = 1KB bursts from tiled vP (L2-shared across blocks).
// Epilogue adds wco . coT^T (K=64) + co_b, writes out once.
// ---------------------------------------------------------------------------
__global__ __launch_bounds__(512, 4) void pos_attn_kernel(
    const unsigned short* __restrict__ qkvT, const unsigned short* __restrict__ vP,
    const unsigned short* __restrict__ wco, const unsigned short* __restrict__ coT,
    const float* __restrict__ co_b, float* __restrict__ out)
{
    __shared__ unsigned short Ks[64 * 72];
    __shared__ unsigned short Ps[2][64 * 136];   // P^T [j][i 128], +8 pad
    const int b  = blockIdx.x;
    const int j0 = blockIdx.y * 64;
    const unsigned short* qb = qkvT + (long)b * 786432;                       // q_lin
    const unsigned short* kb = qkvT + (long)b * 786432 + 262144 + (long)j0 * 64; // kT
    const unsigned short* vb = vP + (long)b * 512 * 4096;
    const int tid = threadIdx.x, lane = tid & 63, wave = tid >> 6;
    const int l15 = lane & 15, quad = lane >> 4;
    const int il = wave * 16 + quad * 4;
    const int lfrag = (l15 * 4 + quad) * 8;      // per-lane offset in a 1KB frag
    const int vfrag = l15 * 32 + quad * 8;       // per-lane offset in a V frag tile

    // stage Ks (64 x 64 = 4096 shorts, fully linear, one pass of 512 thr x 8)
    {
        int flat = tid * 8;
        *(floatx4*)&Ks[(flat >> 6) * 72 + (flat & 63)] = *(const floatx4*)(kb + flat);
    }
    const floatx4 vz = {0.f, 0.f, 0.f, 0.f};
    floatx4 oacc[4][4];
#pragma unroll
    for (int mi = 0; mi < 4; ++mi) for (int nt = 0; nt < 4; ++nt) oacc[mi][nt] = vz;
    __syncthreads();

    // E phase for i-block ib -> Ps[buf]
    auto e_phase = [&](int ib, int buf) {
        const unsigned short* qr = qb + (long)(ib * 8 + wave) * 1024;
        bf16x8 a0 = *(const bf16x8*)(qr + lfrag);
        bf16x8 a1 = *(const bf16x8*)(qr + 512 + lfrag);
        floatx4 e[4];
#pragma unroll
        for (int nt = 0; nt < 4; ++nt) e[nt] = vz;
#pragma unroll
        for (int nt = 0; nt < 4; ++nt) {
            bf16x8 bf = *(const bf16x8*)&Ks[(nt * 16 + l15) * 72 + quad * 8];
            e[nt] = __builtin_amdgcn_mfma_f32_16x16x32_bf16(a0, bf, e[nt], 0, 0, 0);
        }
#pragma unroll
        for (int nt = 0; nt < 4; ++nt) {
            bf16x8 bf = *(const bf16x8*)&Ks[(nt * 16 + l15) * 72 + 32 + quad * 8];
            e[nt] = __builtin_amdgcn_mfma_f32_16x16x32_bf16(a1, bf, e[nt], 0, 0, 0);
        }
#pragma unroll
        for (int nt = 0; nt < 4; ++nt) {
            uint2v p;
            p.x = pack_bf16(exp2f(e[nt][0]), exp2f(e[nt][1]));
            p.y = pack_bf16(exp2f(e[nt][2]), exp2f(e[nt][3]));
            *(uint2v*)&Ps[buf][(nt * 16 + l15) * 136 + il] = p;
        }
    };

    e_phase(0, 0);
    __syncthreads();

    for (int ib = 0; ib < 32; ++ib) {
        const int cur = ib & 1;
        // --- out += V' * P (m: 64 c-rows/wave, n=j 64, k=i 128) ---
        const unsigned short* vt = vb + (long)ib * 65536 + (wave * 4) * 2048 + vfrag;
        __builtin_amdgcn_s_setprio(1);
#pragma unroll
        for (int ks = 0; ks < 4; ++ks) {
            bf16x8 af[4];
#pragma unroll
            for (int mi = 0; mi < 4; ++mi)
                af[mi] = *(const bf16x8*)(vt + mi * 2048 + ks * 512);
#pragma unroll
            for (int nt = 0; nt < 4; ++nt) {
                bf16x8 bf = *(const bf16x8*)&Ps[cur][(nt * 16 + l15) * 136 + ks * 32 + quad * 8];
#pragma unroll
                for (int mi = 0; mi < 4; ++mi)
                    oacc[mi][nt] = __builtin_amdgcn_mfma_f32_16x16x32_bf16(af[mi], bf, oacc[mi][nt], 0, 0, 0);
            }
        }
        __builtin_amdgcn_s_setprio(0);
        if (ib < 31) e_phase(ib + 1, 1 - cur);
        __syncthreads();
    }

    // --- fused channel output: out += wco . coT^T (m=c, n=j, k=q 64) ---
    const unsigned short* cob = coT + ((long)b * 4096 + j0) * 64;
#pragma unroll
    for (int ks = 0; ks < 2; ++ks) {
        bf16x8 aw[4];
#pragma unroll
        for (int mi = 0; mi < 4; ++mi)
            aw[mi] = *(const bf16x8*)(wco + (long)((wave * 4 + mi) * 16 + l15) * 64 + ks * 32 + quad * 8);
#pragma unroll
        for (int nt = 0; nt < 4; ++nt) {
            bf16x8 bf = *(const bf16x8*)(cob + (long)(nt * 16 + l15) * 64 + ks * 32 + quad * 8);
#pragma unroll
            for (int mi = 0; mi < 4; ++mi)
                oacc[mi][nt] = __builtin_amdgcn_mfma_f32_16x16x32_bf16(aw[mi], bf, oacc[mi][nt], 0, 0, 0);
        }
    }
    // --- store (single write of out) ---
#pragma unroll
    for (int mi = 0; mi < 4; ++mi) {
        const int c = (wave * 4 + mi) * 16 + quad * 4;
#pragma unroll
        for (int nt = 0; nt < 4; ++nt) {
            const int j = j0 + nt * 16 + l15;
#pragma unroll
            for (int r = 0; r < 4; ++r)
                out[((long)b * 512 + c + r) * 4096 + j] = oacc[mi][nt][r] + co_b[c + r];
        }
    }
}

// ---------------------------------------------------------------------------
// x [B,512,4096] fp32 -> xT [B,4096,512] bf16 (64x64 LDS tile transpose)
// ---------------------------------------------------------------------------
__global__ __launch_bounds__(256) void transpose_x(
    const float* __restrict__ x, unsigned short* __restrict__ xT)
{
    __shared__ unsigned short T[64 * 66];
    const int b  = blockIdx.z;
    const int n0 = blockIdx.x * 64;
    const int c0 = blockIdx.y * 64;
    const int tid = threadIdx.x;
    const int r8 = tid >> 5;
    const int col2 = (tid & 31) * 2;
#pragma unroll
    for (int k = 0; k < 8; ++k) {
        const int c = r8 + k * 8;
        floatx2 v = *(const floatx2*)(x + ((long)(b * 512 + c0 + c)) * 4096 + n0 + col2);
        *(unsigned int*)&T[c * 66 + col2] = pack_bf16(v.x, v.y);
    }
    __syncthreads();
#pragma unroll
    for (int k = 0; k < 8; ++k) {
        const int n = r8 + k * 8;
        unsigned int pk = (unsigned int)T[col2 * 66 + n] | ((unsigned int)T[(col2 + 1) * 66 + n] << 16);
        *(unsigned int*)(xT + ((long)(b * 4096 + n0 + n)) * 512 + c0 + col2) = pk;
    }
}

// ---------------------------------------------------------------------------
// fp32 weights -> bf16, fused layouts:
//  wqkv [192][512] = [wq*LOG2E; wk; wcv],  wcqck [128][512] = [wcq; wck],
//  wv [512][512],  wco [512][64].  Biases: bqkv[192], bcqck[128] (fp32).
// ---------------------------------------------------------------------------
__global__ __launch_bounds__(256) void convert_weights(
    const float* __restrict__ pq_w, const float* __restrict__ pk_w,
    const float* __restrict__ pv_w, const float* __restrict__ cq_w,
    const float* __restrict__ ck_w, const float* __restrict__ cv_w,
    const float* __restrict__ co_w,
    const float* __restrict__ pq_b, const float* __restrict__ pk_b,
    const float* __restrict__ cv_b, const float* __restrict__ cq_b,
    const float* __restrict__ ck_b,
    unsigned short* __restrict__ dst, float* __restrict__ biases)
{
    const int total = 458752;
    const int gtid = blockIdx.x * 256 + threadIdx.x;
    for (int i = gtid; i < total; i += gridDim.x * 256) {
        float v;
        if (i < 98304) {
            int r = i >> 9, k = i & 511;
            if (r < 64)       v = pq_w[r * 512 + k] * LOG2E;
            else if (r < 128) v = pk_w[(r - 64) * 512 + k];
            else              v = cv_w[(r - 128) * 512 + k];
        } else if (i < 163840) {
            int j = i - 98304; int r = j >> 9, k = j & 511;
            v = (r < 64) ? cq_w[r * 512 + k] : ck_w[(r - 64) * 512 + k];
        } else if (i < 425984) v = pv_w[i - 163840];
        else                   v = co_w[i - 425984];
        dst[i] = f2bf(v);
    }
    if (gtid < 320) {
        float v;
        if (gtid < 64)       v = pq_b[gtid] * LOG2E;
        else if (gtid < 128) v = pk_b[gtid - 64];
        else if (gtid < 192) v = cv_b[gtid - 128];
        else if (gtid < 256) v = cq_b[gtid - 192];
        else                 v = ck_b[gtid - 256];
        biases[gtid] = v;
    }
}

// ---------------------------------------------------------------------------
// channel softmax over q (64 logits, fp32) -> c_attn bf16
// ---------------------------------------------------------------------------
__global__ __launch_bounds__(64) void chan_softmax(
    const float* __restrict__ ce, unsigned short* __restrict__ ca)
{
    const int p = blockIdx.x, b = blockIdx.y, q = threadIdx.x;
    const long base = ((long)b * 64 + p) * 64;
    float v = ce[base + q];
    float m = v;
#pragma unroll
    for (int s = 32; s >= 1; s >>= 1) m = fmaxf(m, __shfl_xor(m, s));
    float e = exp2f((v - m) * LOG2E);
    float sum = e;
#pragma unroll
    for (int s = 32; s >= 1; s >>= 1) sum += __shfl_xor(sum, s);
    ca[base + q] = f2bf(e / sum);
}

// ---------------------------------------------------------------------------
extern "C" void kernel_launch(void* const* d_in, const int* in_sizes, int n_in,
                              void* d_out, int out_size, void* d_ws, size_t ws_size,
                              hipStream_t stream) {
    const float* x    = (const float*)d_in[0];
    const float* pv_b = (const float*)d_in[6];
    const float* co_b = (const float*)d_in[14];
    float* out = (float*)d_out;
    char* ws = (char*)d_ws;

    // ws layout (bytes)
    constexpr long OFF_XT   = 0;                        // bf16 [8][4096][512]
    constexpr long OFF_QKV  = 33554432;                 // bf16 [8][ q_lin | kT | cvT ] (3 x 262144 shorts)
    constexpr long OFF_VP   = OFF_QKV + 12582912;       // bf16 [8][512][4096] (v * rcp_l, TILED)
    constexpr long OFF_CQCK = OFF_VP + 33554432;        // bf16 [8][128][4096] (cq|ck)
    constexpr long OFF_COT  = OFF_CQCK + 8388608;       // bf16 [8][4096][64]
    constexpr long OFF_RCL  = OFF_COT + 4194304;        // fp32 [8][4096]
    constexpr long OFF_CE   = OFF_RCL + 131072;         // fp32 [8][64][64]
    constexpr long OFF_CAT  = OFF_CE + 131072;          // bf16 [8][64][64]
    constexpr long OFF_WB   = OFF_CAT + 65536;          // bf16 weights (458752)
    constexpr long OFF_BIAS = OFF_WB + 917504;          // fp32 [320]

    unsigned short* xT   = (unsigned short*)(ws + OFF_XT);
    unsigned short* qkvT = (unsigned short*)(ws + OFF_QKV);
    unsigned short* vP   = (unsigned short*)(ws + OFF_VP);
    unsigned short* cqck = (unsigned short*)(ws + OFF_CQCK);
    unsigned short* coT  = (unsigned short*)(ws + OFF_COT);
    float*          rcl  = (float*)(ws + OFF_RCL);
    float*          ce   = (float*)(ws + OFF_CE);
    unsigned short* cat  = (unsigned short*)(ws + OFF_CAT);
    unsigned short* wb   = (unsigned short*)(ws + OFF_WB);
    float*          bias = (float*)(ws + OFF_BIAS);
    unsigned short* wqkv  = wb;
    unsigned short* wcqck = wb + 98304;
    unsigned short* wv    = wb + 163840;
    unsigned short* wco   = wb + 425984;
    float* bqkv  = bias;
    float* bcqck = bias + 192;

    // 0) convert weights (+bias concat), transpose x
    convert_weights<<<dim3(64), 256, 0, stream>>>(
        (const float*)d_in[1], (const float*)d_in[3], (const float*)d_in[5],
        (const float*)d_in[7], (const float*)d_in[9], (const float*)d_in[11],
        (const float*)d_in[13],
        (const float*)d_in[2], (const float*)d_in[4], (const float*)d_in[12],
        (const float*)d_in[8], (const float*)d_in[10], wb, bias);
    transpose_x<<<dim3(64, 8, 8), 256, 0, stream>>>(x, xT);

    // 1) fused projections: q_lin|kT|cvT (SPECIAL=2); cqck [b][128][4096]
    tn_gemm<128, 192, true, false, 2><<<dim3(1, 32, 8), 256, 0, stream>>>(
        xT, 512, 2097152L, wqkv, 512, 0L, qkvT, 192, 786432L,
        nullptr, bqkv, nullptr, 0L, 512, 1);
    tn_gemm<128, 128, true, false><<<dim3(32, 1, 8), 256, 0, stream>>>(
        wcqck, 512, 0L, xT, 512, 2097152L, cqck, 4096, 524288L,
        bcqck, nullptr, nullptr, 0L, 512, 1);

    // 2) softmax denominators -> rcp_l  (4 blocks/CU occupancy regrid)
    rowsum_kernel<<<dim3(8, 64), 256, 0, stream>>>(qkvT, rcl);

    // 3) v' = (Wv x + b) * rcp_l  (column scale by position), TILED output
    tn_gemm<128, 128, true, false, 1><<<dim3(32, 4, 8), 256, 0, stream>>>(
        wv, 512, 0L, xT, 512, 2097152L, vP, 4096, 2097152L,
        pv_b, nullptr, rcl, 4096L, 512, 1);

    // 4) channel attention: c_energy (split-K x32 atomic), softmax, c_outT
    hipMemsetAsync(ce, 0, 8 * 64 * 64 * sizeof(float), stream);
    tn_gemm<64, 64, false, true><<<dim3(1, 1, 256), 256, 0, stream>>>(
        cqck, 4096, 524288L, cqck + 262144, 4096, 524288L, ce, 64, 4096L,
        nullptr, nullptr, nullptr, 0L, 128, 32);
    chan_softmax<<<dim3(64, 8), 64, 0, stream>>>(ce, cat);
    tn_gemm<128, 64, true, false><<<dim3(1, 32, 8), 256, 0, stream>>>(
        qkvT + 524288, 64, 786432L, cat, 64, 4096L, coT, 64, 262144L,
        nullptr, nullptr, nullptr, 0L, 64, 1);

    // 5) fused position attention + channel output epilogue -> out (1 write)
    pos_attn_kernel<<<dim3(8, 64), 512, 0, stream>>>(qkvT, vP, wco, coT, co_b, out);
}

// Round 6
// 462.287 us; speedup vs baseline: 1.1835x; 1.1835x over previous
//
#include <hip/hip_runtime.h>
#include <stdint.h>

// ---------------------------------------------------------------------------
// Dual attention (DANet): pos attention + channel attention, fused pipeline.
// B=8, C=512, CQ=64, H=W=64, HW=4096.  All GEMMs bf16 MFMA 16x16x32, fp32 acc.
//
// pos_out[c,j] = sum_i v'[c,i] * exp(e[i,j]),  v' = (Wv x + b) * rcp_l[i],
//   rcp_l[i] = 1 / sum_j exp(e[i,j])   (no max subtraction: |e| <~ 13)
// LOG2E folded into wq/pq_b at convert time -> exp2 direct.
//
// v7: v5 layouts (all VMEM loads dense bursts).  pos_attn = round-4 exact
//   (NO setprio: it desyncs the 2 co-resident blocks' ib phase -> vP L2
//   thrash + partial-line out writeback, +60us measured).
//   rowsum: j-split x2 (i-tile 128 kept), partial sums + combine kernel.
//   qkv/cqck/coT GEMMs retiled 64x96 / 64x64 / 64x64 for 2-4 blocks/CU
//   (were 256 blocks = 1 wave/SIMD).
// NOTE: pos_attn register budget is EXACTLY 64 arch + 64 acc = 128 = the
// 4-wave/SIMD boundary.  Do not add live state to pos_attn.
// ---------------------------------------------------------------------------

#define LOG2E 1.44269504088896340736f

typedef __attribute__((ext_vector_type(8))) __bf16 bf16x8;
typedef __attribute__((ext_vector_type(4))) float floatx4;
typedef __attribute__((ext_vector_type(2))) float floatx2;
typedef __attribute__((ext_vector_type(2))) unsigned int uint2v;

static __device__ __forceinline__ unsigned short f2bf(float f) {
    union { float f; uint32_t u; } v; v.f = f;
    uint32_t r = v.u + 0x7fffu + ((v.u >> 16) & 1u);   // RNE
    return (unsigned short)(r >> 16);
}

// pack two fp32 -> bf16x2 (round-half-up: +0x8000, take high16 via v_perm)
static __device__ __forceinline__ unsigned int pack_bf16(float a, float b) {
    union { float f; uint32_t u; } x, y; x.f = a; y.f = b;
    return __builtin_amdgcn_perm(y.u + 0x8000u, x.u + 0x8000u, 0x07060302u);
}

// ---------------------------------------------------------------------------
// Generic TN GEMM: C[m,n] = (sum_k A[m,k]*B[n,k] + bias_m[m] + bias_n[n])
//                  * scale_n[n].   A,B bf16 K-contiguous. BK=64.
// SPECIAL=1 (VTILE): write C in pos_attn's V-fragment-linear layout
//   idx = (n>>7)*65536 + (m>>4)*2048 + ((n>>5)&3)*512 + (m&15)*32
//       + ((n>>3)&3)*8 + (n&7)     (m = c, n = i)
// SPECIAL=2 (QKV split): n<64 -> q_lin frag-linear; n in [64,192) ->
//   kT/cvT row-major lda 64 at base (n>>6)*262144.
// ---------------------------------------------------------------------------
template<int BM, int BN, bool OUT_BF16, bool ATOMIC, int SPECIAL = 0>
__global__ __launch_bounds__(256) void tn_gemm(
    const unsigned short* __restrict__ A, int lda, long sA,
    const unsigned short* __restrict__ B, int ldb, long sB,
    void* __restrict__ C, int ldc, long sC,
    const float* __restrict__ bias_m, const float* __restrict__ bias_n,
    const float* __restrict__ scale_n, long sScale,
    int K, int kchunks)
{
    constexpr int PK = 72;                 // 64 + 8 pad
    __shared__ unsigned short As[BM * PK];
    __shared__ unsigned short Bs[BN * PK];
    const int bz = blockIdx.z;
    const int b  = bz / kchunks;
    const int kc = bz % kchunks;
    const int m0 = blockIdx.y * BM;
    const int n0 = blockIdx.x * BN;
    const unsigned short* Ab = A + (long)b * sA + (long)m0 * lda + (long)kc * K;
    const unsigned short* Bb = B + (long)b * sB + (long)n0 * ldb + (long)kc * K;
    const int tid = threadIdx.x;
    const int lane = tid & 63, wave = tid >> 6;
    const int l15 = lane & 15, quad = lane >> 4;
    constexpr int NT  = BN / 16;
    constexpr int MPW = BM / 64;
    constexpr int AL  = BM / 32;
    constexpr int BL  = BN / 32;

    const floatx4 vz = {0.f, 0.f, 0.f, 0.f};
    floatx4 acc[MPW][NT];
    for (int i = 0; i < MPW; ++i) for (int j = 0; j < NT; ++j) acc[i][j] = vz;

    const int nK = K >> 6;
    for (int k0 = 0; k0 < nK; ++k0) {
        floatx4 ar[AL], br[BL];
#pragma unroll
        for (int L = 0; L < AL; ++L) {
            int flat = L * 2048 + tid * 8;
            ar[L] = *(const floatx4*)(Ab + (long)(flat >> 6) * lda + (k0 << 6) + (flat & 63));
        }
#pragma unroll
        for (int L = 0; L < BL; ++L) {
            int flat = L * 2048 + tid * 8;
            br[L] = *(const floatx4*)(Bb + (long)(flat >> 6) * ldb + (k0 << 6) + (flat & 63));
        }
        __syncthreads();
#pragma unroll
        for (int L = 0; L < AL; ++L) {
            int flat = L * 2048 + tid * 8;
            *(floatx4*)&As[(flat >> 6) * PK + (flat & 63)] = ar[L];
        }
#pragma unroll
        for (int L = 0; L < BL; ++L) {
            int flat = L * 2048 + tid * 8;
            *(floatx4*)&Bs[(flat >> 6) * PK + (flat & 63)] = br[L];
        }
        __syncthreads();
#pragma unroll
        for (int ks = 0; ks < 2; ++ks) {
            bf16x8 af[MPW];
#pragma unroll
            for (int mi = 0; mi < MPW; ++mi)
                af[mi] = *(const bf16x8*)&As[((wave * MPW + mi) * 16 + l15) * PK + ks * 32 + quad * 8];
#pragma unroll
            for (int nt = 0; nt < NT; ++nt) {
                bf16x8 bf = *(const bf16x8*)&Bs[(nt * 16 + l15) * PK + ks * 32 + quad * 8];
#pragma unroll
                for (int mi = 0; mi < MPW; ++mi)
                    acc[mi][nt] = __builtin_amdgcn_mfma_f32_16x16x32_bf16(af[mi], bf, acc[mi][nt], 0, 0, 0);
            }
        }
    }
    // epilogue (C/D layout: col = lane&15, row = quad*4 + r)
#pragma unroll
    for (int mi = 0; mi < MPW; ++mi) {
        const int mb = m0 + (wave * MPW + mi) * 16 + quad * 4;
#pragma unroll
        for (int nt = 0; nt < NT; ++nt) {
            const int n = n0 + nt * 16 + l15;
            const float bn = bias_n ? bias_n[n] : 0.f;
            const float cs = scale_n ? scale_n[(long)b * sScale + n] : 1.f;
            floatx4 a = acc[mi][nt];
#pragma unroll
            for (int r = 0; r < 4; ++r) {
                const int m = mb + r;
                float v = (a[r] + (bias_m ? bias_m[m] : 0.f) + bn) * cs;
                long idx;
                if (SPECIAL == 1)
                    idx = (long)b * sC + ((long)(n >> 7) * 65536 + (m >> 4) * 2048
                        + ((n >> 5) & 3) * 512 + (m & 15) * 32 + ((n >> 3) & 3) * 8 + (n & 7));
                else if (SPECIAL == 2) {
                    if (n < 64)   // q_lin fragment-linear
                        idx = (long)b * sC + ((long)(m >> 4) * 1024 + (n >> 5) * 512
                            + (m & 15) * 32 + ((n >> 3) & 3) * 8 + (n & 7));
                    else          // kT / cvT row-major lda 64
                        idx = (long)b * sC + (long)(n >> 6) * 262144 + (long)m * 64 + (n & 63);
                } else
                    idx = (long)b * sC + (long)m * ldc + n;
                if (ATOMIC)         atomicAdd((float*)C + idx, v);
                else if (OUT_BF16)  ((unsigned short*)C)[idx] = f2bf(v);
                else                ((float*)C)[idx] = v;
            }
        }
    }
}

// ---------------------------------------------------------------------------
// Partial row sums: lpart[jh][b][i] = sum_{j in half jh} exp2(E'[i,j]).
// q from q_lin (1KB frag bursts), K from kT [4096][64] (linear staging).
// v7: j-split x2 (16 K-tiles of 128 per block), i-tile 128, 8-wave blocks,
// grid (8,32,2) = 512 blocks -> 2 blocks/CU (4 waves/SIMD); per-block
// staging halves while per-block MFMA:staging ratio is unchanged.
// K-tile double-buffered in LDS, one barrier per tile.
// ---------------------------------------------------------------------------
__global__ __launch_bounds__(512, 4) void rowsum_kernel(
    const unsigned short* __restrict__ qkvT, float* __restrict__ lpart)
{
    __shared__ unsigned short Ks[2][128 * 72];
    const int b  = blockIdx.x;
    const int i0 = blockIdx.y * 128;
    const int jh = blockIdx.z;
    const unsigned short* qv = qkvT + (long)b * 786432;            // q_lin
    const unsigned short* kb = qkvT + (long)b * 786432 + 262144 + (long)jh * 131072; // kT half
    const int tid = threadIdx.x, lane = tid & 63, wave = tid >> 6;
    const int l15 = lane & 15, quad = lane >> 4;

    bf16x8 af[2];
#pragma unroll
    for (int ks = 0; ks < 2; ++ks)
        af[ks] = *(const bf16x8*)(qv + (long)((i0 >> 4) + wave) * 1024 + ks * 512 + (l15 * 4 + quad) * 8);

    // stage tile 0 (128 rows x 64 = 8192 shorts, linear): 2 passes of 512x8
#pragma unroll
    for (int p = 0; p < 2; ++p) {
        int flat = p * 4096 + tid * 8;
        *(floatx4*)&Ks[0][(flat >> 6) * 72 + (flat & 63)] = *(const floatx4*)(kb + flat);
    }
    float rs[4] = {0.f, 0.f, 0.f, 0.f};
    const floatx4 vz = {0.f, 0.f, 0.f, 0.f};
    __syncthreads();

    for (int jb = 0; jb < 16; ++jb) {
        const int cur = jb & 1;
        floatx4 stage[2];
        if (jb < 15) {
#pragma unroll
            for (int p = 0; p < 2; ++p) {
                int flat = p * 4096 + tid * 8;
                stage[p] = *(const floatx4*)(kb + (jb + 1) * 8192 + flat);
            }
        }
        floatx4 e[8];
#pragma unroll
        for (int nt = 0; nt < 8; ++nt) e[nt] = vz;
#pragma unroll
        for (int ks = 0; ks < 2; ++ks)
#pragma unroll
            for (int nt = 0; nt < 8; ++nt) {
                bf16x8 bf = *(const bf16x8*)&Ks[cur][(nt * 16 + l15) * 72 + ks * 32 + quad * 8];
                e[nt] = __builtin_amdgcn_mfma_f32_16x16x32_bf16(af[ks], bf, e[nt], 0, 0, 0);
            }
#pragma unroll
        for (int nt = 0; nt < 8; ++nt)
#pragma unroll
            for (int r = 0; r < 4; ++r)
                rs[r] += exp2f(e[nt][r]);
        if (jb < 15) {
#pragma unroll
            for (int p = 0; p < 2; ++p) {
                int flat = p * 4096 + tid * 8;
                *(floatx4*)&Ks[1 - cur][(flat >> 6) * 72 + (flat & 63)] = stage[p];
            }
        }
        __syncthreads();
    }
#pragma unroll
    for (int r = 0; r < 4; ++r) {
        float v = rs[r];
        v += __shfl_xor(v, 1); v += __shfl_xor(v, 2);
        v += __shfl_xor(v, 4); v += __shfl_xor(v, 8);
        if (l15 == 0)
            lpart[(long)jh * 32768 + (long)b * 4096 + i0 + wave * 16 + quad * 4 + r] = v;
    }
}

// combine partial sums -> reciprocals: rcl[i] = 1/(lp[0][i] + lp[1][i])
__global__ __launch_bounds__(256) void rcp_combine(
    const float* __restrict__ lp, float* __restrict__ rcl)
{
    const int i = blockIdx.x * 256 + threadIdx.x;   // 32768 total
    rcl[i] = 1.0f / (lp[i] + lp[32768 + i]);
}

// ---------------------------------------------------------------------------
// Fused position attention + channel-output epilogue (round-4 exact).
// Block = (batch, j-tile 64), 512 threads (8 waves); c-tile = 512 (full).
// Per i-iter (128): ONE barrier. Region: PV(ib) reads Ps[cur] || E(ib+1)
// writes Ps[1-cur].  E: q frags = 1KB bursts from q_lin;
// PV: V frags = 1KB bursts from tiled vP (L2-shared across blocks).
// NO setprio: block co-phase controls the vP L2 working set (round-5 lesson).
// Epilogue adds wco . coT^T (K=64) + co_b, writes out once.
// ---------------------------------------------------------------------------
__global__ __launch_bounds__(512, 4) void pos_attn_kernel(
    const unsigned short* __restrict__ qkvT, const unsigned short* __restrict__ vP,
    const unsigned short* __restrict__ wco, const unsigned short* __restrict__ coT,
    const float* __restrict__ co_b, float* __restrict__ out)
{
    __shared__ unsigned short Ks[64 * 72];
    __shared__ unsigned short Ps[2][64 * 136];   // P^T [j][i 128], +8 pad
    const int b  = blockIdx.x;
    const int j0 = blockIdx.y * 64;
    const unsigned short* qb = qkvT + (long)b * 786432;                       // q_lin
    const unsigned short* kb = qkvT + (long)b * 786432 + 262144 + (long)j0 * 64; // kT
    const unsigned short* vb = vP + (long)b * 512 * 4096;
    const int tid = threadIdx.x, lane = tid & 63, wave = tid >> 6;
    const int l15 = lane & 15, quad = lane >> 4;
    const int il = wave * 16 + quad * 4;
    const int lfrag = (l15 * 4 + quad) * 8;      // per-lane offset in a 1KB frag
    const int vfrag = l15 * 32 + quad * 8;       // per-lane offset in a V frag tile

    // stage Ks (64 x 64 = 4096 shorts, fully linear, one pass of 512 thr x 8)
    {
        int flat = tid * 8;
        *(floatx4*)&Ks[(flat >> 6) * 72 + (flat & 63)] = *(const floatx4*)(kb + flat);
    }
    const floatx4 vz = {0.f, 0.f, 0.f, 0.f};
    floatx4 oacc[4][4];
#pragma unroll
    for (int mi = 0; mi < 4; ++mi) for (int nt = 0; nt < 4; ++nt) oacc[mi][nt] = vz;
    __syncthreads();

    // E phase for i-block ib -> Ps[buf]
    auto e_phase = [&](int ib, int buf) {
        const unsigned short* qr = qb + (long)(ib * 8 + wave) * 1024;
        bf16x8 a0 = *(const bf16x8*)(qr + lfrag);
        bf16x8 a1 = *(const bf16x8*)(qr + 512 + lfrag);
        floatx4 e[4];
#pragma unroll
        for (int nt = 0; nt < 4; ++nt) e[nt] = vz;
#pragma unroll
        for (int nt = 0; nt < 4; ++nt) {
            bf16x8 bf = *(const bf16x8*)&Ks[(nt * 16 + l15) * 72 + quad * 8];
            e[nt] = __builtin_amdgcn_mfma_f32_16x16x32_bf16(a0, bf, e[nt], 0, 0, 0);
        }
#pragma unroll
        for (int nt = 0; nt < 4; ++nt) {
            bf16x8 bf = *(const bf16x8*)&Ks[(nt * 16 + l15) * 72 + 32 + quad * 8];
            e[nt] = __builtin_amdgcn_mfma_f32_16x16x32_bf16(a1, bf, e[nt], 0, 0, 0);
        }
#pragma unroll
        for (int nt = 0; nt < 4; ++nt) {
            uint2v p;
            p.x = pack_bf16(exp2f(e[nt][0]), exp2f(e[nt][1]));
            p.y = pack_bf16(exp2f(e[nt][2]), exp2f(e[nt][3]));
            *(uint2v*)&Ps[buf][(nt * 16 + l15) * 136 + il] = p;
        }
    };

    e_phase(0, 0);
    __syncthreads();

    for (int ib = 0; ib < 32; ++ib) {
        const int cur = ib & 1;
        // --- out += V' * P (m: 64 c-rows/wave, n=j 64, k=i 128) ---
        const unsigned short* vt = vb + (long)ib * 65536 + (wave * 4) * 2048 + vfrag;
#pragma unroll
        for (int ks = 0; ks < 4; ++ks) {
            bf16x8 af[4];
#pragma unroll
            for (int mi = 0; mi < 4; ++mi)
                af[mi] = *(const bf16x8*)(vt + mi * 2048 + ks * 512);
#pragma unroll
            for (int nt = 0; nt < 4; ++nt) {
                bf16x8 bf = *(const bf16x8*)&Ps[cur][(nt * 16 + l15) * 136 + ks * 32 + quad * 8];
#pragma unroll
                for (int mi = 0; mi < 4; ++mi)
                    oacc[mi][nt] = __builtin_amdgcn_mfma_f32_16x16x32_bf16(af[mi], bf, oacc[mi][nt], 0, 0, 0);
            }
        }
        if (ib < 31) e_phase(ib + 1, 1 - cur);
        __syncthreads();
    }

    // --- fused channel output: out += wco . coT^T (m=c, n=j, k=q 64) ---
    const unsigned short* cob = coT + ((long)b * 4096 + j0) * 64;
#pragma unroll
    for (int ks = 0; ks < 2; ++ks) {
        bf16x8 aw[4];
#pragma unroll
        for (int mi = 0; mi < 4; ++mi)
            aw[mi] = *(const bf16x8*)(wco + (long)((wave * 4 + mi) * 16 + l15) * 64 + ks * 32 + quad * 8);
#pragma unroll
        for (int nt = 0; nt < 4; ++nt) {
            bf16x8 bf = *(const bf16x8*)(cob + (long)(nt * 16 + l15) * 64 + ks * 32 + quad * 8);
#pragma unroll
            for (int mi = 0; mi < 4; ++mi)
                oacc[mi][nt] = __builtin_amdgcn_mfma_f32_16x16x32_bf16(aw[mi], bf, oacc[mi][nt], 0, 0, 0);
        }
    }
    // --- store (single write of out) ---
#pragma unroll
    for (int mi = 0; mi < 4; ++mi) {
        const int c = (wave * 4 + mi) * 16 + quad * 4;
#pragma unroll
        for (int nt = 0; nt < 4; ++nt) {
            const int j = j0 + nt * 16 + l15;
#pragma unroll
            for (int r = 0; r < 4; ++r)
                out[((long)b * 512 + c + r) * 4096 + j] = oacc[mi][nt][r] + co_b[c + r];
        }
    }
}

// ---------------------------------------------------------------------------
// x [B,512,4096] fp32 -> xT [B,4096,512] bf16 (64x64 LDS tile transpose)
// ---------------------------------------------------------------------------
__global__ __launch_bounds__(256) void transpose_x(
    const float* __restrict__ x, unsigned short* __restrict__ xT)
{
    __shared__ unsigned short T[64 * 66];
    const int b  = blockIdx.z;
    const int n0 = blockIdx.x * 64;
    const int c0 = blockIdx.y * 64;
    const int tid = threadIdx.x;
    const int r8 = tid >> 5;
    const int col2 = (tid & 31) * 2;
#pragma unroll
    for (int k = 0; k < 8; ++k) {
        const int c = r8 + k * 8;
        floatx2 v = *(const floatx2*)(x + ((long)(b * 512 + c0 + c)) * 4096 + n0 + col2);
        *(unsigned int*)&T[c * 66 + col2] = pack_bf16(v.x, v.y);
    }
    __syncthreads();
#pragma unroll
    for (int k = 0; k < 8; ++k) {
        const int n = r8 + k * 8;
        unsigned int pk = (unsigned int)T[col2 * 66 + n] | ((unsigned int)T[(col2 + 1) * 66 + n] << 16);
        *(unsigned int*)(xT + ((long)(b * 4096 + n0 + n)) * 512 + c0 + col2) = pk;
    }
}

// ---------------------------------------------------------------------------
// fp32 weights -> bf16, fused layouts:
//  wqkv [192][512] = [wq*LOG2E; wk; wcv],  wcqck [128][512] = [wcq; wck],
//  wv [512][512],  wco [512][64].  Biases: bqkv[192], bcqck[128] (fp32).
// ---------------------------------------------------------------------------
__global__ __launch_bounds__(256) void convert_weights(
    const float* __restrict__ pq_w, const float* __restrict__ pk_w,
    const float* __restrict__ pv_w, const float* __restrict__ cq_w,
    const float* __restrict__ ck_w, const float* __restrict__ cv_w,
    const float* __restrict__ co_w,
    const float* __restrict__ pq_b, const float* __restrict__ pk_b,
    const float* __restrict__ cv_b, const float* __restrict__ cq_b,
    const float* __restrict__ ck_b,
    unsigned short* __restrict__ dst, float* __restrict__ biases)
{
    const int total = 458752;
    const int gtid = blockIdx.x * 256 + threadIdx.x;
    for (int i = gtid; i < total; i += gridDim.x * 256) {
        float v;
        if (i < 98304) {
            int r = i >> 9, k = i & 511;
            if (r < 64)       v = pq_w[r * 512 + k] * LOG2E;
            else if (r < 128) v = pk_w[(r - 64) * 512 + k];
            else              v = cv_w[(r - 128) * 512 + k];
        } else if (i < 163840) {
            int j = i - 98304; int r = j >> 9, k = j & 511;
            v = (r < 64) ? cq_w[r * 512 + k] : ck_w[(r - 64) * 512 + k];
        } else if (i < 425984) v = pv_w[i - 163840];
        else                   v = co_w[i - 425984];
        dst[i] = f2bf(v);
    }
    if (gtid < 320) {
        float v;
        if (gtid < 64)       v = pq_b[gtid] * LOG2E;
        else if (gtid < 128) v = pk_b[gtid - 64];
        else if (gtid < 192) v = cv_b[gtid - 128];
        else if (gtid < 256) v = cq_b[gtid - 192];
        else                 v = ck_b[gtid - 256];
        biases[gtid] = v;
    }
}

// ---------------------------------------------------------------------------
// channel softmax over q (64 logits, fp32) -> c_attn bf16
// ---------------------------------------------------------------------------
__global__ __launch_bounds__(64) void chan_softmax(
    const float* __restrict__ ce, unsigned short* __restrict__ ca)
{
    const int p = blockIdx.x, b = blockIdx.y, q = threadIdx.x;
    const long base = ((long)b * 64 + p) * 64;
    float v = ce[base + q];
    float m = v;
#pragma unroll
    for (int s = 32; s >= 1; s >>= 1) m = fmaxf(m, __shfl_xor(m, s));
    float e = exp2f((v - m) * LOG2E);
    float sum = e;
#pragma unroll
    for (int s = 32; s >= 1; s >>= 1) sum += __shfl_xor(sum, s);
    ca[base + q] = f2bf(e / sum);
}

// ---------------------------------------------------------------------------
extern "C" void kernel_launch(void* const* d_in, const int* in_sizes, int n_in,
                              void* d_out, int out_size, void* d_ws, size_t ws_size,
                              hipStream_t stream) {
    const float* x    = (const float*)d_in[0];
    const float* pv_b = (const float*)d_in[6];
    const float* co_b = (const float*)d_in[14];
    float* out = (float*)d_out;
    char* ws = (char*)d_ws;

    // ws layout (bytes)
    constexpr long OFF_XT   = 0;                        // bf16 [8][4096][512]
    constexpr long OFF_QKV  = 33554432;                 // bf16 [8][ q_lin | kT | cvT ] (3 x 262144 shorts)
    constexpr long OFF_VP   = OFF_QKV + 12582912;       // bf16 [8][512][4096] (v * rcp_l, TILED)
    constexpr long OFF_CQCK = OFF_VP + 33554432;        // bf16 [8][128][4096] (cq|ck)
    constexpr long OFF_COT  = OFF_CQCK + 8388608;       // bf16 [8][4096][64]
    constexpr long OFF_RCL  = OFF_COT + 4194304;        // fp32 [8][4096]
    constexpr long OFF_CE   = OFF_RCL + 131072;         // fp32 [8][64][64]
    constexpr long OFF_CAT  = OFF_CE + 131072;          // bf16 [8][64][64]
    constexpr long OFF_WB   = OFF_CAT + 65536;          // bf16 weights (458752)
    constexpr long OFF_BIAS = OFF_WB + 917504;          // fp32 [320]

    unsigned short* xT   = (unsigned short*)(ws + OFF_XT);
    unsigned short* qkvT = (unsigned short*)(ws + OFF_QKV);
    unsigned short* vP   = (unsigned short*)(ws + OFF_VP);
    unsigned short* cqck = (unsigned short*)(ws + OFF_CQCK);
    unsigned short* coT  = (unsigned short*)(ws + OFF_COT);
    float*          rcl  = (float*)(ws + OFF_RCL);
    float*          ce   = (float*)(ws + OFF_CE);
    unsigned short* cat  = (unsigned short*)(ws + OFF_CAT);
    unsigned short* wb   = (unsigned short*)(ws + OFF_WB);
    float*          bias = (float*)(ws + OFF_BIAS);
    unsigned short* wqkv  = wb;
    unsigned short* wcqck = wb + 98304;
    unsigned short* wv    = wb + 163840;
    unsigned short* wco   = wb + 425984;
    float* bqkv  = bias;
    float* bcqck = bias + 192;
    // rowsum partials (2 x 8 x 4096 fp32 = 256 KB) live in vP's space:
    // consumed by rcp_combine BEFORE the wv GEMM writes vP.
    float* lpart = (float*)(ws + OFF_VP);

    // 0) convert weights (+bias concat), transpose x
    convert_weights<<<dim3(64), 256, 0, stream>>>(
        (const float*)d_in[1], (const float*)d_in[3], (const float*)d_in[5],
        (const float*)d_in[7], (const float*)d_in[9], (const float*)d_in[11],
        (const float*)d_in[13],
        (const float*)d_in[2], (const float*)d_in[4], (const float*)d_in[12],
        (const float*)d_in[8], (const float*)d_in[10], wb, bias);
    transpose_x<<<dim3(64, 8, 8), 256, 0, stream>>>(x, xT);

    // 1) fused projections: q_lin|kT|cvT (SPECIAL=2, 64x96 tiles -> 1024
    //    blocks = 4/CU); cqck (64x64 tiles -> 1024 blocks)
    tn_gemm<64, 96, true, false, 2><<<dim3(2, 64, 8), 256, 0, stream>>>(
        xT, 512, 2097152L, wqkv, 512, 0L, qkvT, 192, 786432L,
        nullptr, bqkv, nullptr, 0L, 512, 1);
    tn_gemm<64, 64, true, false><<<dim3(64, 2, 8), 256, 0, stream>>>(
        wcqck, 512, 0L, xT, 512, 2097152L, cqck, 4096, 524288L,
        bcqck, nullptr, nullptr, 0L, 512, 1);

    // 2) softmax denominators: j-split partials -> combine to rcp_l
    rowsum_kernel<<<dim3(8, 32, 2), 512, 0, stream>>>(qkvT, lpart);
    rcp_combine<<<dim3(128), 256, 0, stream>>>(lpart, rcl);

    // 3) v' = (Wv x + b) * rcp_l  (column scale by position), TILED output
    tn_gemm<128, 128, true, false, 1><<<dim3(32, 4, 8), 256, 0, stream>>>(
        wv, 512, 0L, xT, 512, 2097152L, vP, 4096, 2097152L,
        pv_b, nullptr, rcl, 4096L, 512, 1);

    // 4) channel attention: c_energy (split-K atomic), softmax, c_outT
    hipMemsetAsync(ce, 0, 8 * 64 * 64 * sizeof(float), stream);
    tn_gemm<64, 64, false, true><<<dim3(1, 1, 64), 256, 0, stream>>>(
        cqck, 4096, 524288L, cqck + 262144, 4096, 524288L, ce, 64, 4096L,
        nullptr, nullptr, nullptr, 0L, 512, 8);
    chan_softmax<<<dim3(64, 8), 64, 0, stream>>>(ce, cat);
    tn_gemm<64, 64, true, false><<<dim3(1, 64, 8), 256, 0, stream>>>(
        qkvT + 524288, 64, 786432L, cat, 64, 4096L, coT, 64, 262144L,
        nullptr, nullptr, nullptr, 0L, 64, 1);

    // 5) fused position attention + channel output epilogue -> out (1 write)
    pos_attn_kernel<<<dim3(8, 64), 512, 0, stream>>>(qkvT, vP, wco, coT, co_b, out);
}